// Round 2
// baseline (26.657 us; speedup 1.0000x reference)
//
#include <hip/hip_runtime.h>
#include <math.h>

namespace {

constexpr int NB = 8;     // batch
constexpr int NS = 48;    // samples
constexpr int NA = 8192;  // atoms
constexpr int BSIZE = 256;
constexpr int CH = 4;     // chunks per (b,s)

// ws layout (floats):
// [WT4 .. WT4 + NB*NA*4)        wt4 table: (w, w*t0, w*t1, w*t2) per (b,n)
// [PB  .. PB + NB*8*8)          per-(b, subblock j) partials: 6 used of 8
// [PS  .. PS + NB*NS*CH*16)     per-(b,s,chunk) partials: 13 used of 16
constexpr int WT4 = 0;
constexpr int PB = NB * NA * 4;        // 262144
constexpr int PS = PB + NB * 8 * 8;    // 262656 (16B-aligned)

template <int CNT>
__device__ inline void blockReduceWrite(const float (&v)[CNT], float* __restrict__ dst,
                                        float* lds, int nwaves) {
  const int lane = threadIdx.x & 63;
  const int wave = threadIdx.x >> 6;
#pragma unroll
  for (int k = 0; k < CNT; ++k) {
    float x = v[k];
#pragma unroll
    for (int off = 32; off; off >>= 1) x += __shfl_xor(x, off, 64);
    if (lane == 0) lds[wave * CNT + k] = x;
  }
  __syncthreads();
  if ((int)threadIdx.x < CNT) {
    float s = 0.f;
    for (int w = 0; w < nwaves; ++w) s += lds[w * CNT + threadIdx.x];
    dst[threadIdx.x] = s;
  }
}

// 64 blocks: b = blk>>3, j = blk&7; 1024 atoms each.
__global__ __launch_bounds__(BSIZE) void prep_kernel(
    const float* __restrict__ truec, const int* __restrict__ mask,
    const int* __restrict__ dna, const int* __restrict__ rna,
    const int* __restrict__ lig, float* __restrict__ ws) {
  __shared__ float lds[(BSIZE / 64) * 6];
  const int blk = blockIdx.x;
  const int b = blk >> 3, j = blk & 7;
  const int nloc = j * 1024 + threadIdx.x * 4;
  const int gbase = b * NA + nloc;
  const float* t = truec + (size_t)b * NA * 3 + 3 * nloc;

  const float4 ta = *(const float4*)(t);
  const float4 tb = *(const float4*)(t + 4);
  const float4 tc = *(const float4*)(t + 8);
  const int4 mk = *(const int4*)(mask + gbase);
  const int4 dn = *(const int4*)(dna + gbase);
  const int4 rn = *(const int4*)(rna + gbase);
  const int4 lg = *(const int4*)(lig + gbase);

  float acc[6];
#pragma unroll
  for (int k = 0; k < 6; ++k) acc[k] = 0.f;

  auto one = [&](int idx, int m, int d, int r, int l, float t0, float t1, float t2) {
    const float mf = (float)m;
    const float w = (1.0f + 5.0f * (float)d + 5.0f * (float)r + 10.0f * (float)l) * mf;
    const float4 o = make_float4(w, w * t0, w * t1, w * t2);
    *(float4*)(ws + (size_t)(gbase + idx) * 4) = o;
    acc[0] += w;
    acc[1] += o.y;
    acc[2] += o.z;
    acc[3] += o.w;
    acc[4] += w * (t0 * t0 + t1 * t1 + t2 * t2);
    acc[5] += mf;
  };

  one(0, mk.x, dn.x, rn.x, lg.x, ta.x, ta.y, ta.z);
  one(1, mk.y, dn.y, rn.y, lg.y, ta.w, tb.x, tb.y);
  one(2, mk.z, dn.z, rn.z, lg.z, tb.z, tb.w, tc.x);
  one(3, mk.w, dn.w, rn.w, lg.w, tc.y, tc.z, tc.w);

  blockReduceWrite<6>(acc, ws + PB + blk * 8, lds, BSIZE / 64);
}

// NB*NS*CH blocks: bs = blk/CH, chunk = blk%CH; 2048 atoms each (2 iters).
__global__ __launch_bounds__(BSIZE) void main_kernel(const float* __restrict__ pred,
                                                     float* __restrict__ ws) {
  __shared__ float lds[(BSIZE / 64) * 13];
  const int blk = blockIdx.x;
  const int bs = blk / CH, chunk = blk % CH;
  const int b = bs / NS;
  const float* p = pred + (size_t)bs * NA * 3;
  const float* wt = ws + (size_t)b * NA * 4;

  float acc[13];
#pragma unroll
  for (int k = 0; k < 13; ++k) acc[k] = 0.f;

  auto atom = [&](float4 q, float p0, float p1, float p2) {
    const float wp0 = q.x * p0, wp1 = q.x * p1, wp2 = q.x * p2;
    acc[0] += wp0 * p0 + wp1 * p1 + wp2 * p2;
    acc[1] += wp0;
    acc[2] += wp1;
    acc[3] += wp2;
    acc[4] += p0 * q.y;
    acc[5] += p0 * q.z;
    acc[6] += p0 * q.w;
    acc[7] += p1 * q.y;
    acc[8] += p1 * q.z;
    acc[9] += p1 * q.w;
    acc[10] += p2 * q.y;
    acc[11] += p2 * q.z;
    acc[12] += p2 * q.w;
  };

#pragma unroll
  for (int it = 0; it < 2; ++it) {
    const int n0 = chunk * 2048 + it * 1024 + threadIdx.x * 4;
    const float4 pa = *(const float4*)(p + 3 * n0);
    const float4 pb = *(const float4*)(p + 3 * n0 + 4);
    const float4 pc = *(const float4*)(p + 3 * n0 + 8);
    const float4 w0 = *(const float4*)(wt + (size_t)n0 * 4);
    const float4 w1 = *(const float4*)(wt + (size_t)n0 * 4 + 4);
    const float4 w2 = *(const float4*)(wt + (size_t)n0 * 4 + 8);
    const float4 w3 = *(const float4*)(wt + (size_t)n0 * 4 + 12);

    atom(w0, pa.x, pa.y, pa.z);
    atom(w1, pa.w, pb.x, pb.y);
    atom(w2, pb.z, pb.w, pc.x);
    atom(w3, pc.y, pc.z, pc.w);
  }

  blockReduceWrite<13>(acc, ws + PS + blk * 16, lds, BSIZE / 64);
}

__global__ __launch_bounds__(NB * NS) void final_kernel(const float* __restrict__ ws,
                                                        const float* __restrict__ scale,
                                                        float* __restrict__ out) {
  __shared__ double bvals[NB][6];
  const int tid = threadIdx.x;  // 0..383, tid = b*NS + s

  if (tid < NB) {
    double s[6] = {0, 0, 0, 0, 0, 0};
    for (int jb = 0; jb < 8; ++jb) {
      const float* q = ws + PB + (tid * 8 + jb) * 8;
#pragma unroll
      for (int k = 0; k < 6; ++k) s[k] += (double)q[k];
    }
#pragma unroll
    for (int k = 0; k < 6; ++k) bvals[tid][k] = s[k];
  }
  __syncthreads();

  const int b = tid / NS;
  double sums[13];
#pragma unroll
  for (int k = 0; k < 13; ++k) sums[k] = 0.0;
  for (int c = 0; c < CH; ++c) {
    const float* q = ws + PS + (size_t)(tid * CH + c) * 16;
#pragma unroll
    for (int k = 0; k < 13; ++k) sums[k] += (double)q[k];
  }

  const double wsum = bvals[b][0];
  const double st0 = bvals[b][1], st1 = bvals[b][2], st2 = bvals[b][3];
  const double stt = bvals[b][4];
  const double msum = bvals[b][5];

  const double spp = sums[0];
  const double sp0 = sums[1], sp1 = sums[2], sp2 = sums[3];

  const double inv = 1.0 / wsum;
  const double Sp[3] = {sp0, sp1, sp2};
  const double St[3] = {st0, st1, st2};

  double H[3][3];
#pragma unroll
  for (int i = 0; i < 3; ++i)
#pragma unroll
    for (int j = 0; j < 3; ++j) H[i][j] = sums[4 + 3 * i + j] - Sp[i] * St[j] * inv;

  const double Sq = spp - (sp0 * sp0 + sp1 * sp1 + sp2 * sp2) * inv;
  const double Sy = stt - (st0 * st0 + st1 * st1 + st2 * st2) * inv;

  // K = H^T H  (symmetric PSD)
  double K[3][3];
#pragma unroll
  for (int i = 0; i < 3; ++i)
#pragma unroll
    for (int j = 0; j < 3; ++j)
      K[i][j] = H[0][i] * H[0][j] + H[1][i] * H[1][j] + H[2][i] * H[2][j];

  const double q = (K[0][0] + K[1][1] + K[2][2]) / 3.0;
  const double p1 = K[0][1] * K[0][1] + K[0][2] * K[0][2] + K[1][2] * K[1][2];
  const double a0 = K[0][0] - q, a1 = K[1][1] - q, a2 = K[2][2] - q;
  const double p2 = a0 * a0 + a1 * a1 + a2 * a2 + 2.0 * p1;
  double e1, e2, e3;
  if (p2 <= 1e-300) {
    e1 = e2 = e3 = q;
  } else {
    const double pp = sqrt(p2 / 6.0);
    const double ip = 1.0 / pp;
    const double B00 = a0 * ip, B11 = a1 * ip, B22 = a2 * ip;
    const double B01 = K[0][1] * ip, B02 = K[0][2] * ip, B12 = K[1][2] * ip;
    double r = 0.5 * (B00 * (B11 * B22 - B12 * B12) - B01 * (B01 * B22 - B12 * B02) +
                      B02 * (B01 * B12 - B11 * B02));
    r = fmin(1.0, fmax(-1.0, r));
    const double phi = acos(r) / 3.0;
    e1 = q + 2.0 * pp * cos(phi);
    e3 = q + 2.0 * pp * cos(phi + 2.0943951023931953);
    e2 = 3.0 * q - e1 - e3;
  }
  const double s1 = sqrt(fmax(e1, 0.0));
  const double s2 = sqrt(fmax(e2, 0.0));
  const double s3 = sqrt(fmax(e3, 0.0));

  const double detH =
      H[0][0] * (H[1][1] * H[2][2] - H[1][2] * H[2][1]) -
      H[0][1] * (H[1][0] * H[2][2] - H[1][2] * H[2][0]) +
      H[0][2] * (H[1][0] * H[2][1] - H[1][1] * H[2][0]);
  const double d = (detH > 0.0) ? 1.0 : ((detH < 0.0) ? -1.0 : 0.0);

  const double trRtH = s1 + s2 + d * s3;
  const double cost = Sq + Sy - 2.0 * trRtH;
  const double denom = msum + 1e-6;
  const double per_sample = cost / denom * (double)scale[tid];

  double c = per_sample * (1.0 / (3.0 * (double)NS * (double)NB));

#pragma unroll
  for (int off = 32; off; off >>= 1) c += __shfl_xor(c, off, 64);

  __shared__ double lds[NB * NS / 64];
  if ((tid & 63) == 0) lds[tid >> 6] = c;
  __syncthreads();
  if (tid == 0) {
    double s = 0.0;
    for (int w = 0; w < NB * NS / 64; ++w) s += lds[w];
    out[0] = (float)s;
  }
}

}  // namespace

extern "C" void kernel_launch(void* const* d_in, const int* in_sizes, int n_in,
                              void* d_out, int out_size, void* d_ws, size_t ws_size,
                              hipStream_t stream) {
  const float* pred = (const float*)d_in[0];
  const float* truec = (const float*)d_in[1];
  const int* mask = (const int*)d_in[2];
  const int* dna = (const int*)d_in[3];
  const int* rna = (const int*)d_in[4];
  const int* lig = (const int*)d_in[5];
  const float* scale = (const float*)d_in[6];
  float* ws = (float*)d_ws;
  float* out = (float*)d_out;

  prep_kernel<<<64, BSIZE, 0, stream>>>(truec, mask, dna, rna, lig, ws);
  main_kernel<<<NB * NS * CH, BSIZE, 0, stream>>>(pred, ws);
  final_kernel<<<1, NB * NS, 0, stream>>>(ws, scale, out);
}